// Round 2
// baseline (1012.329 us; speedup 1.0000x reference)
//
#include <hip/hip_runtime.h>

// GAT layer, N=8192, D=256, fused flash-style attention with 4-way column
// split (flash split-KV) for occupancy. Split-bf16 (hi+lo) MFMA for the logit
// chain (h, g, QK^T); plain bf16 for PV and the output GEMM.

typedef __attribute__((ext_vector_type(8))) short bf16x8;
typedef __attribute__((ext_vector_type(4))) float f32x4;

#define NN 8192
#define DD 256
#define NSPLIT 4
#define CHUNK (NN / NSPLIT)

__device__ __forceinline__ short f2bf(float f) {
  union { float f; unsigned u; } v; v.f = f;
  unsigned r = v.u + 0x7fffu + ((v.u >> 16) & 1u);  // RNE
  return (short)(r >> 16);
}
__device__ __forceinline__ float bf2f(short b) {
  union { unsigned u; float f; } v; v.u = ((unsigned)(unsigned short)b) << 16;
  return v.f;
}

// f32 -> (hi, lo) bf16 split, elementwise
__global__ __launch_bounds__(256) void cvt_split_kernel(const float* __restrict__ in,
                                                        short* __restrict__ hi,
                                                        short* __restrict__ lo, int n) {
  for (int i = blockIdx.x * blockDim.x + threadIdx.x; i < n; i += gridDim.x * blockDim.x) {
    float f = in[i];
    short h = f2bf(f);
    hi[i] = h;
    lo[i] = f2bf(f - bf2f(h));
  }
}

// featT[c][i] = bf16(feat[i][c])   (PV B-operand wants K-major = feat^T)
__global__ __launch_bounds__(256) void featT_kernel(const float* __restrict__ feat,
                                                    short* __restrict__ fT) {
  int c = blockIdx.y;
  int i = blockIdx.x * 256 + threadIdx.x;
  fT[c * NN + i] = f2bf(feat[i * DD + c]);
}

// 256x256 f32 -> transposed bf16 (optionally split hi/lo)
__global__ __launch_bounds__(256) void transpose_split_kernel(const float* __restrict__ in,
                                                              short* __restrict__ tHi,
                                                              short* __restrict__ tLo) {
  int r = blockIdx.x, c = threadIdx.x;
  float f = in[r * DD + c];
  short h = f2bf(f);
  tHi[c * DD + r] = h;
  if (tLo) tLo[c * DD + r] = f2bf(f - bf2f(h));
}

// C[64x64 tile] = A @ BT^T over K=256.  Optional split (Alo/BTlo 3-term),
// optional second plain product (A2@BT2) accumulated, optional ELU epilogue.
__global__ __launch_bounds__(256) void gemm_bt64_kernel(
    const short* __restrict__ Ahi, const short* __restrict__ Alo,
    const short* __restrict__ BThi, const short* __restrict__ BTlo,
    const short* __restrict__ A2, const short* __restrict__ BT2,
    short* __restrict__ outHi, short* __restrict__ outLo,
    float* __restrict__ outF, int doElu) {
  const int lane = threadIdx.x & 63;
  const int w = threadIdx.x >> 6;
  const int l15 = lane & 15;
  const int koff = (lane >> 4) * 8;
  const int row0 = blockIdx.x * 64 + w * 16;
  const int col0 = blockIdx.y * 64;
  f32x4 acc[4] = {};
  const int aoff = (row0 + l15) * DD + koff;
#pragma unroll
  for (int kk = 0; kk < 8; ++kk) {
    bf16x8 ah = *(const bf16x8*)(Ahi + aoff + kk * 32);
#pragma unroll
    for (int cf = 0; cf < 4; ++cf) {
      int boff = (col0 + cf * 16 + l15) * DD + kk * 32 + koff;
      bf16x8 bh = *(const bf16x8*)(BThi + boff);
      acc[cf] = __builtin_amdgcn_mfma_f32_16x16x32_bf16(ah, bh, acc[cf], 0, 0, 0);
      if (Alo) {
        bf16x8 al = *(const bf16x8*)(Alo + aoff + kk * 32);
        acc[cf] = __builtin_amdgcn_mfma_f32_16x16x32_bf16(al, bh, acc[cf], 0, 0, 0);
      }
      if (BTlo) {
        bf16x8 bl = *(const bf16x8*)(BTlo + boff);
        acc[cf] = __builtin_amdgcn_mfma_f32_16x16x32_bf16(ah, bl, acc[cf], 0, 0, 0);
      }
    }
  }
  if (A2) {
#pragma unroll
    for (int kk = 0; kk < 8; ++kk) {
      bf16x8 ah = *(const bf16x8*)(A2 + aoff + kk * 32);
#pragma unroll
      for (int cf = 0; cf < 4; ++cf) {
        bf16x8 bh = *(const bf16x8*)(BT2 + (col0 + cf * 16 + l15) * DD + kk * 32 + koff);
        acc[cf] = __builtin_amdgcn_mfma_f32_16x16x32_bf16(ah, bh, acc[cf], 0, 0, 0);
      }
    }
  }
  const int crow = row0 + (lane >> 4) * 4;
#pragma unroll
  for (int cf = 0; cf < 4; ++cf) {
    int col = col0 + cf * 16 + l15;
#pragma unroll
    for (int r = 0; r < 4; ++r) {
      float v = acc[cf][r];
      if (doElu) v = (v > 0.f) ? v : expm1f(v);
      if (outF) outF[(crow + r) * DD + col] = v;
      if (outHi) {
        short hb = f2bf(v);
        outHi[(crow + r) * DD + col] = hb;
        if (outLo) outLo[(crow + r) * DD + col] = f2bf(v - bf2f(hb));
      }
    }
  }
}

// ax[i] = h[i,:]·a1, ay[i] = h[i,:]·a2
__global__ __launch_bounds__(256) void axay_kernel(const short* __restrict__ hHi,
                                                   const short* __restrict__ hLo,
                                                   const float* __restrict__ a1,
                                                   const float* __restrict__ a2,
                                                   float* __restrict__ ax,
                                                   float* __restrict__ ay) {
  const int lane = threadIdx.x & 63;
  const int w = threadIdx.x >> 6;
  const int row = blockIdx.x * 4 + w;
  float s1 = 0.f, s2 = 0.f;
#pragma unroll
  for (int j = 0; j < 4; ++j) {
    int k = lane * 4 + j;
    float hv = bf2f(hHi[row * DD + k]) + bf2f(hLo[row * DD + k]);
    s1 += hv * a1[k];
    s2 += hv * a2[k];
  }
#pragma unroll
  for (int m = 1; m < 64; m <<= 1) {
    s1 += __shfl_xor(s1, m);
    s2 += __shfl_xor(s2, m);
  }
  if (lane == 0) { ax[row] = s1; ay[row] = s2; }
}

// Fused flash attention over the graph, split-KV over NSPLIT column chunks.
// Block = 32 rows x 1 chunk, 256 threads (4 waves: wr x wc).  Emits
// unnormalized bf16 numerator + f32 (m, l) per row per chunk.
__global__ __launch_bounds__(256, 4) void attn_kernel(
    const short* __restrict__ gHi, const short* __restrict__ gLo,
    const short* __restrict__ hHi, const short* __restrict__ hLo,
    const short* __restrict__ fT, const float* __restrict__ ax,
    const float* __restrict__ ay, const int* __restrict__ adj,
    short* __restrict__ numPart, float* __restrict__ mPart,
    float* __restrict__ lPart) {
  __shared__ float sS[32][65];
  __shared__ short sP[32][72];
  __shared__ float sScale[32];

  const int tid = threadIdx.x;
  const int lane = tid & 63;
  const int w = tid >> 6;
  const int wr = w >> 1, wc = w & 1;
  const int row0 = blockIdx.x * 32;
  const int chunk = blockIdx.y;
  const int jbase = chunk * CHUNK;
  const int l15 = lane & 15;
  const int koff = (lane >> 4) * 8;
  const int srow = wr * 16 + (lane >> 4) * 4;

  // Q-hoist: g fragments (hi+lo) for this wave's 16 rows, all K=256
  bf16x8 ghi[8], glo[8];
  {
    int go = (row0 + wr * 16 + l15) * DD + koff;
#pragma unroll
    for (int kk = 0; kk < 8; ++kk) {
      ghi[kk] = *(const bf16x8*)(gHi + go + kk * 32);
      glo[kk] = *(const bf16x8*)(gLo + go + kk * 32);
    }
  }
  float ay4[4];
#pragma unroll
  for (int r = 0; r < 4; ++r) ay4[r] = ay[row0 + srow + r];

  const int smrow = tid >> 3;
  const int smc0 = (tid & 7) * 8;
  float m_run = -__builtin_inff();
  float l_run = 0.f;
  f32x4 accpv[8] = {};

  for (int jt = 0; jt < CHUNK; jt += 64) {
    const int j0 = jbase + jt;
    // ---- prefetch adj + ax for this tile (hide HBM latency under MFMAs) ----
    int a8[2][4];
    float axv2[2];
#pragma unroll
    for (int cf = 0; cf < 2; ++cf) {
      int lcol = wc * 32 + cf * 16 + l15;
      axv2[cf] = ax[j0 + lcol];
#pragma unroll
      for (int r = 0; r < 4; ++r)
        a8[cf][r] = adj[(row0 + srow + r) * NN + j0 + lcol];
    }
    // ---- S = g @ h^T (split precision, 3-term) ----
    f32x4 accs[2] = {};
#pragma unroll
    for (int kk = 0; kk < 8; ++kk) {
#pragma unroll
      for (int cf = 0; cf < 2; ++cf) {
        int ho = (j0 + wc * 32 + cf * 16 + l15) * DD + kk * 32 + koff;
        bf16x8 bh = *(const bf16x8*)(hHi + ho);
        bf16x8 bl = *(const bf16x8*)(hLo + ho);
        accs[cf] = __builtin_amdgcn_mfma_f32_16x16x32_bf16(ghi[kk], bh, accs[cf], 0, 0, 0);
        accs[cf] = __builtin_amdgcn_mfma_f32_16x16x32_bf16(glo[kk], bh, accs[cf], 0, 0, 0);
        accs[cf] = __builtin_amdgcn_mfma_f32_16x16x32_bf16(ghi[kk], bl, accs[cf], 0, 0, 0);
      }
    }
    // ---- bias + leaky + mask -> LDS ----
#pragma unroll
    for (int cf = 0; cf < 2; ++cf) {
      int lcol = wc * 32 + cf * 16 + l15;
#pragma unroll
      for (int r = 0; r < 4; ++r) {
        float v = accs[cf][r] + axv2[cf] + ay4[r];
        v = (v > 0.f) ? v : 0.2f * v;
        sS[srow + r][lcol] = (a8[cf][r] > 0) ? v : -9.0e15f;
      }
    }
    __syncthreads();
    // ---- online softmax (8 lanes/row) ----
    float p8[8];
    float tmax = -__builtin_inff();
#pragma unroll
    for (int c = 0; c < 8; ++c) {
      p8[c] = sS[smrow][smc0 + c];
      tmax = fmaxf(tmax, p8[c]);
    }
    tmax = fmaxf(tmax, __shfl_xor(tmax, 1));
    tmax = fmaxf(tmax, __shfl_xor(tmax, 2));
    tmax = fmaxf(tmax, __shfl_xor(tmax, 4));
    float m_new = fmaxf(m_run, tmax);
    float scale = __expf(m_run - m_new);
    float psum = 0.f;
    union { short s[8]; bf16x8 v; } pu;
#pragma unroll
    for (int c = 0; c < 8; ++c) {
      float p = __expf(p8[c] - m_new);
      psum += p;
      pu.s[c] = f2bf(p);
    }
    *(bf16x8*)(&sP[smrow][smc0]) = pu.v;
    psum += __shfl_xor(psum, 1);
    psum += __shfl_xor(psum, 2);
    psum += __shfl_xor(psum, 4);
    l_run = l_run * scale + psum;
    m_run = m_new;
    if ((tid & 7) == 0) sScale[smrow] = scale;
    __syncthreads();
    // ---- PV: rescale accumulator, then P @ feat ----
    float sc4[4];
#pragma unroll
    for (int r = 0; r < 4; ++r) sc4[r] = sScale[srow + r];
#pragma unroll
    for (int cf = 0; cf < 8; ++cf) {
#pragma unroll
      for (int r = 0; r < 4; ++r) accpv[cf][r] *= sc4[r];
    }
#pragma unroll
    for (int kk = 0; kk < 2; ++kk) {
      bf16x8 pf = *(const bf16x8*)(&sP[wr * 16 + l15][kk * 32 + koff]);
#pragma unroll
      for (int cf = 0; cf < 8; ++cf) {
        bf16x8 bf = *(const bf16x8*)(fT + (wc * 128 + cf * 16 + l15) * NN + j0 + kk * 32 + koff);
        accpv[cf] = __builtin_amdgcn_mfma_f32_16x16x32_bf16(pf, bf, accpv[cf], 0, 0, 0);
      }
    }
    __syncthreads();
  }
  // ---- emit partials (unnormalized numerator + m,l) ----
  if ((tid & 7) == 0) {
    mPart[chunk * NN + row0 + smrow] = m_run;
    lPart[chunk * NN + row0 + smrow] = l_run;
  }
  short* np = numPart + (size_t)chunk * NN * DD;
#pragma unroll
  for (int cf = 0; cf < 8; ++cf) {
    int col = wc * 128 + cf * 16 + l15;
#pragma unroll
    for (int r = 0; r < 4; ++r)
      np[(row0 + srow + r) * DD + col] = f2bf(accpv[cf][r]);
  }
}

// hp[row][col] = (sum_i num_i * exp(m_i - m*)) / (sum_i l_i * exp(m_i - m*))
__global__ __launch_bounds__(256) void combine_kernel(
    const short* __restrict__ numPart, const float* __restrict__ mPart,
    const float* __restrict__ lPart, short* __restrict__ hp) {
  const int row = blockIdx.x;
  const int col = threadIdx.x;
  float m[NSPLIT], l[NSPLIT];
  float ms = -__builtin_inff();
#pragma unroll
  for (int i = 0; i < NSPLIT; ++i) {
    m[i] = mPart[i * NN + row];
    l[i] = lPart[i * NN + row];
    ms = fmaxf(ms, m[i]);
  }
  float denom = 0.f, num = 0.f;
  const size_t idx = (size_t)row * DD + col;
#pragma unroll
  for (int i = 0; i < NSPLIT; ++i) {
    float wgt = __expf(m[i] - ms);
    denom += l[i] * wgt;
    num += bf2f(numPart[(size_t)i * NN * DD + idx]) * wgt;
  }
  hp[idx] = f2bf(num / denom);
}

extern "C" void kernel_launch(void* const* d_in, const int* in_sizes, int n_in,
                              void* d_out, int out_size, void* d_ws, size_t ws_size,
                              hipStream_t stream) {
  const float* feat = (const float*)d_in[0];
  const int*   adj  = (const int*)d_in[1];
  const float* W    = (const float*)d_in[2];
  const float* a1   = (const float*)d_in[3];
  const float* a2   = (const float*)d_in[4];
  const float* a12  = (const float*)d_in[5];
  const float* W1   = (const float*)d_in[6];
  const float* W2   = (const float*)d_in[7];
  float* out = (float*)d_out;
  (void)in_sizes; (void)n_in; (void)out_size; (void)ws_size;

  char* ws = (char*)d_ws;
  size_t off = 0;
  auto alloc = [&](size_t b) { void* p = ws + off; off += (b + 255) & ~(size_t)255; return p; };
  short* featHi = (short*)alloc((size_t)NN * DD * 2);
  short* featLo = (short*)alloc((size_t)NN * DD * 2);
  short* fT     = (short*)alloc((size_t)NN * DD * 2);
  short* hHi    = (short*)alloc((size_t)NN * DD * 2);
  short* hLo    = (short*)alloc((size_t)NN * DD * 2);
  short* gHi    = (short*)alloc((size_t)NN * DD * 2);
  short* gLo    = (short*)alloc((size_t)NN * DD * 2);
  short* hp     = (short*)alloc((size_t)NN * DD * 2);
  short* WTh    = (short*)alloc((size_t)DD * DD * 2);
  short* WTl    = (short*)alloc((size_t)DD * DD * 2);
  short* A12Th  = (short*)alloc((size_t)DD * DD * 2);
  short* A12Tl  = (short*)alloc((size_t)DD * DD * 2);
  short* W1T    = (short*)alloc((size_t)DD * DD * 2);
  short* W2T    = (short*)alloc((size_t)DD * DD * 2);
  float* axv    = (float*)alloc((size_t)NN * 4);
  float* ayv    = (float*)alloc((size_t)NN * 4);
  short* numPart = (short*)alloc((size_t)NSPLIT * NN * DD * 2);
  float* mPart   = (float*)alloc((size_t)NSPLIT * NN * 4);
  float* lPart   = (float*)alloc((size_t)NSPLIT * NN * 4);

  cvt_split_kernel<<<2048, 256, 0, stream>>>(feat, featHi, featLo, NN * DD);
  featT_kernel<<<dim3(NN / 256, DD), 256, 0, stream>>>(feat, fT);
  transpose_split_kernel<<<DD, DD, 0, stream>>>(W, WTh, WTl);
  transpose_split_kernel<<<DD, DD, 0, stream>>>(a12, A12Th, A12Tl);
  transpose_split_kernel<<<DD, DD, 0, stream>>>(W1, W1T, nullptr);
  transpose_split_kernel<<<DD, DD, 0, stream>>>(W2, W2T, nullptr);
  gemm_bt64_kernel<<<dim3(NN / 64, DD / 64), 256, 0, stream>>>(
      featHi, featLo, WTh, WTl, nullptr, nullptr, hHi, hLo, nullptr, 0);
  gemm_bt64_kernel<<<dim3(NN / 64, DD / 64), 256, 0, stream>>>(
      hHi, hLo, A12Th, A12Tl, nullptr, nullptr, gHi, gLo, nullptr, 0);
  axay_kernel<<<NN / 4, 256, 0, stream>>>(hHi, hLo, a1, a2, axv, ayv);
  attn_kernel<<<dim3(NN / 32, NSPLIT), 256, 0, stream>>>(
      gHi, gLo, hHi, hLo, fT, axv, ayv, adj, numPart, mPart, lPart);
  combine_kernel<<<NN, DD, 0, stream>>>(numPart, mPart, lPart, hp);
  gemm_bt64_kernel<<<dim3(NN / 64, DD / 64), 256, 0, stream>>>(
      featHi, nullptr, W1T, nullptr, hp, W2T, nullptr, nullptr, out, 1);
}

// Round 3
// 423.707 us; speedup vs baseline: 2.3892x; 2.3892x over previous
//
#include <hip/hip_runtime.h>

// GAT layer, N=8192, D=256. Flash-style fused attention, R3:
//  - h-tile (hi+lo) LDS-staged via global_load_lds with pre-swizzled source
//  - wave-per-column-group QK^T (A=g hoisted in 128 VGPRs, B=h from LDS)
//  - fT register prefetch overlapped with softmax; lgkm-only barriers keep
//    stage loads in flight; full __syncthreads at loop top drains them.
// Split-bf16 (hi+lo) 3-term MFMA for the logit chain; plain bf16 elsewhere.

typedef __attribute__((ext_vector_type(8))) short bf16x8;
typedef __attribute__((ext_vector_type(4))) float f32x4;

#define NN 8192
#define DD 256
#define NSPLIT 2
#define CHUNK (NN / NSPLIT)
#define KVB 64
#define BM 32
#define NT (CHUNK / KVB)

#define BAR_LGKM() asm volatile("s_waitcnt lgkmcnt(0)\n\ts_barrier" ::: "memory")

__device__ __forceinline__ short f2bf(float f) {
  union { float f; unsigned u; } v; v.f = f;
  unsigned r = v.u + 0x7fffu + ((v.u >> 16) & 1u);  // RNE
  return (short)(r >> 16);
}
__device__ __forceinline__ float bf2f(short b) {
  union { unsigned u; float f; } v; v.u = ((unsigned)(unsigned short)b) << 16;
  return v.f;
}

typedef __attribute__((address_space(3))) unsigned lds_u32;
typedef const __attribute__((address_space(1))) unsigned glb_u32;
__device__ __forceinline__ void gl2lds16(const void* g, void* l) {
  __builtin_amdgcn_global_load_lds((glb_u32*)g, (lds_u32*)l, 16, 0, 0);
}

// f32 -> (hi, lo) bf16 split, elementwise
__global__ __launch_bounds__(256) void cvt_split_kernel(const float* __restrict__ in,
                                                        short* __restrict__ hi,
                                                        short* __restrict__ lo, int n) {
  for (int i = blockIdx.x * blockDim.x + threadIdx.x; i < n; i += gridDim.x * blockDim.x) {
    float f = in[i];
    short h = f2bf(f);
    hi[i] = h;
    lo[i] = f2bf(f - bf2f(h));
  }
}

// featT[c][i] = bf16(feat[i][c])
__global__ __launch_bounds__(256) void featT_kernel(const float* __restrict__ feat,
                                                    short* __restrict__ fT) {
  int c = blockIdx.y;
  int i = blockIdx.x * 256 + threadIdx.x;
  fT[c * NN + i] = f2bf(feat[i * DD + c]);
}

// 256x256 f32 -> transposed bf16 (optionally split hi/lo)
__global__ __launch_bounds__(256) void transpose_split_kernel(const float* __restrict__ in,
                                                              short* __restrict__ tHi,
                                                              short* __restrict__ tLo) {
  int r = blockIdx.x, c = threadIdx.x;
  float f = in[r * DD + c];
  short h = f2bf(f);
  tHi[c * DD + r] = h;
  if (tLo) tLo[c * DD + r] = f2bf(f - bf2f(h));
}

// C[64x64 tile] = A @ BT^T over K=256 (+optional split / second product / ELU)
__global__ __launch_bounds__(256) void gemm_bt64_kernel(
    const short* __restrict__ Ahi, const short* __restrict__ Alo,
    const short* __restrict__ BThi, const short* __restrict__ BTlo,
    const short* __restrict__ A2, const short* __restrict__ BT2,
    short* __restrict__ outHi, short* __restrict__ outLo,
    float* __restrict__ outF, int doElu) {
  const int lane = threadIdx.x & 63;
  const int w = threadIdx.x >> 6;
  const int l15 = lane & 15;
  const int koff = (lane >> 4) * 8;
  const int row0 = blockIdx.x * 64 + w * 16;
  const int col0 = blockIdx.y * 64;
  f32x4 acc[4] = {};
  const int aoff = (row0 + l15) * DD + koff;
#pragma unroll
  for (int kk = 0; kk < 8; ++kk) {
    bf16x8 ah = *(const bf16x8*)(Ahi + aoff + kk * 32);
#pragma unroll
    for (int cf = 0; cf < 4; ++cf) {
      int boff = (col0 + cf * 16 + l15) * DD + kk * 32 + koff;
      bf16x8 bh = *(const bf16x8*)(BThi + boff);
      acc[cf] = __builtin_amdgcn_mfma_f32_16x16x32_bf16(ah, bh, acc[cf], 0, 0, 0);
      if (Alo) {
        bf16x8 al = *(const bf16x8*)(Alo + aoff + kk * 32);
        acc[cf] = __builtin_amdgcn_mfma_f32_16x16x32_bf16(al, bh, acc[cf], 0, 0, 0);
      }
      if (BTlo) {
        bf16x8 bl = *(const bf16x8*)(BTlo + boff);
        acc[cf] = __builtin_amdgcn_mfma_f32_16x16x32_bf16(ah, bl, acc[cf], 0, 0, 0);
      }
    }
  }
  if (A2) {
#pragma unroll
    for (int kk = 0; kk < 8; ++kk) {
      bf16x8 ah = *(const bf16x8*)(A2 + aoff + kk * 32);
#pragma unroll
      for (int cf = 0; cf < 4; ++cf) {
        bf16x8 bh = *(const bf16x8*)(BT2 + (col0 + cf * 16 + l15) * DD + kk * 32 + koff);
        acc[cf] = __builtin_amdgcn_mfma_f32_16x16x32_bf16(ah, bh, acc[cf], 0, 0, 0);
      }
    }
  }
  const int crow = row0 + (lane >> 4) * 4;
#pragma unroll
  for (int cf = 0; cf < 4; ++cf) {
    int col = col0 + cf * 16 + l15;
#pragma unroll
    for (int r = 0; r < 4; ++r) {
      float v = acc[cf][r];
      if (doElu) v = (v > 0.f) ? v : expm1f(v);
      if (outF) outF[(crow + r) * DD + col] = v;
      if (outHi) {
        short hb = f2bf(v);
        outHi[(crow + r) * DD + col] = hb;
        if (outLo) outLo[(crow + r) * DD + col] = f2bf(v - bf2f(hb));
      }
    }
  }
}

// ax[i] = h[i,:]·a1, ay[i] = h[i,:]·a2
__global__ __launch_bounds__(256) void axay_kernel(const short* __restrict__ hHi,
                                                   const short* __restrict__ hLo,
                                                   const float* __restrict__ a1,
                                                   const float* __restrict__ a2,
                                                   float* __restrict__ ax,
                                                   float* __restrict__ ay) {
  const int lane = threadIdx.x & 63;
  const int w = threadIdx.x >> 6;
  const int row = blockIdx.x * 4 + w;
  float s1 = 0.f, s2 = 0.f;
#pragma unroll
  for (int j = 0; j < 4; ++j) {
    int k = lane * 4 + j;
    float hv = bf2f(hHi[row * DD + k]) + bf2f(hLo[row * DD + k]);
    s1 += hv * a1[k];
    s2 += hv * a2[k];
  }
#pragma unroll
  for (int m = 1; m < 64; m <<= 1) {
    s1 += __shfl_xor(s1, m);
    s2 += __shfl_xor(s2, m);
  }
  if (lane == 0) { ax[row] = s1; ay[row] = s2; }
}

// Fused flash attention, split-KV over NSPLIT chunks.
// Block = 32 rows, 256 threads / 4 waves. Wave w owns columns w*16..w*16+15
// of each 64-col tile for QK^T; A-frags (g, hi+lo, 32 rows) hoisted in regs.
// h-tile staged in LDS (XOR-swizzled) via global_load_lds.
__global__ __launch_bounds__(256, 2) void attn_kernel(
    const short* __restrict__ gHi, const short* __restrict__ gLo,
    const short* __restrict__ hHi, const short* __restrict__ hLo,
    const short* __restrict__ fT, const float* __restrict__ ax,
    const float* __restrict__ ay, const int* __restrict__ adj,
    short* __restrict__ numPart, float* __restrict__ mPart,
    float* __restrict__ lPart) {
  __shared__ short sH[KVB * DD];    // hi tile, swizzled, 32KB
  __shared__ short sHlo[KVB * DD];  // lo tile, swizzled, 32KB
  __shared__ float sS[BM][65];
  __shared__ short sP[BM][72];
  __shared__ float sScale[BM];
  __shared__ float sL[BM];

  const int tid = threadIdx.x;
  const int lane = tid & 63;
  const int w = tid >> 6;
  const int l15 = lane & 15;
  const int koff = (lane >> 4) * 8;     // element offset within K-slice
  const int row0 = blockIdx.x * BM;
  const int chunk = blockIdx.y;
  const int jbase = chunk * CHUNK;
  const int crow = (lane >> 4) * 4;     // MFMA C-layout row base (within 16)

  // ---- hoist g A-frags: rows rg*16+l15, dims kk*32+koff (hi+lo) ----
  bf16x8 ghi[2][8], glo[2][8];
#pragma unroll
  for (int rg = 0; rg < 2; ++rg)
#pragma unroll
    for (int kk = 0; kk < 8; ++kk) {
      int go = (row0 + rg * 16 + l15) * DD + kk * 32 + koff;
      ghi[rg][kk] = *(const bf16x8*)(gHi + go);
      glo[rg][kk] = *(const bf16x8*)(gLo + go);
    }
  float ay8[2][4];
#pragma unroll
  for (int rg = 0; rg < 2; ++rg)
#pragma unroll
    for (int r = 0; r < 4; ++r) ay8[rg][r] = ay[row0 + rg * 16 + crow + r];

  // ---- staging helper: h-tile rows [jrow, jrow+64) -> sH/sHlo, swizzled ----
  auto stage = [&](int jrow) {
#pragma unroll
    for (int R = 0; R < 8; ++R) {
      int dstb = R * 4096 + w * 1024 + lane * 16;   // linear byte in 32KB buf
      int lr = dstb >> 9;                            // local row (512B rows)
      int srcb = (dstb & 511) ^ ((lr & 7) << 4);     // pre-swizzled source col
      int so = (jrow + lr) * DD + (srcb >> 1);
      gl2lds16(hHi + so, (char*)sH + dstb);
      gl2lds16(hLo + so, (char*)sHlo + dstb);
    }
  };

  const int smrow = tid >> 3;
  const int smc0 = (tid & 7) * 8;
  float m_run = -__builtin_inff();
  float l_run = 0.f;
  f32x4 accpv[2][4] = {};  // [rowgroup][dim-frag]: 32 rows x 64 dims per wave

  // prologue: stage tile 0
  stage(jbase);
  __syncthreads();

  for (int t = 0; t < NT; ++t) {
    const int j0 = jbase + t * KVB;
    // ---- adj + ax prefetch (consumed at mask epilogue) ----
    const int mycol = w * 16 + l15;
    float axv = ax[j0 + mycol];
    int a8[2][4];
#pragma unroll
    for (int rg = 0; rg < 2; ++rg)
#pragma unroll
      for (int r = 0; r < 4; ++r)
        a8[rg][r] = adj[(size_t)(row0 + rg * 16 + crow + r) * NN + j0 + mycol];
    // ---- QK^T: B-frags from swizzled LDS, 3-term split ----
    f32x4 accs[2] = {};
    {
      const int lr = w * 16 + l15;
      const int rb = lr * 512;
      const int swz = (lr & 7) << 4;
#pragma unroll
      for (int kk = 0; kk < 8; ++kk) {
        int bo = rb + ((kk * 64 + ((lane >> 4) * 16)) ^ swz);
        bf16x8 bh = *(const bf16x8*)((const char*)sH + bo);
        bf16x8 bl = *(const bf16x8*)((const char*)sHlo + bo);
        accs[0] = __builtin_amdgcn_mfma_f32_16x16x32_bf16(ghi[0][kk], bh, accs[0], 0, 0, 0);
        accs[0] = __builtin_amdgcn_mfma_f32_16x16x32_bf16(glo[0][kk], bh, accs[0], 0, 0, 0);
        accs[0] = __builtin_amdgcn_mfma_f32_16x16x32_bf16(ghi[0][kk], bl, accs[0], 0, 0, 0);
        accs[1] = __builtin_amdgcn_mfma_f32_16x16x32_bf16(ghi[1][kk], bh, accs[1], 0, 0, 0);
        accs[1] = __builtin_amdgcn_mfma_f32_16x16x32_bf16(glo[1][kk], bh, accs[1], 0, 0, 0);
        accs[1] = __builtin_amdgcn_mfma_f32_16x16x32_bf16(ghi[1][kk], bl, accs[1], 0, 0, 0);
      }
    }
    // ---- bias + leaky + mask -> sS ----
#pragma unroll
    for (int rg = 0; rg < 2; ++rg)
#pragma unroll
      for (int r = 0; r < 4; ++r) {
        float v = accs[rg][r] + axv + ay8[rg][r];
        v = (v > 0.f) ? v : 0.2f * v;
        sS[rg * 16 + crow + r][mycol] = (a8[rg][r] > 0) ? v : -9.0e15f;
      }
    BAR_LGKM();  // h-LDS(t) consumed, sS visible; stage loads NOT drained
    // ---- stage next h-tile (stays in flight until loop-top syncthreads) ----
    if (t + 1 < NT) stage(j0 + KVB);
    // ---- fT register prefetch for PV (hidden under softmax) ----
    bf16x8 vstage[4][2];
#pragma unroll
    for (int cf = 0; cf < 4; ++cf)
#pragma unroll
      for (int kk = 0; kk < 2; ++kk)
        vstage[cf][kk] = *(const bf16x8*)(fT + (size_t)(w * 64 + cf * 16 + l15) * NN +
                                          j0 + kk * 32 + koff);
    // ---- online softmax (8 lanes/row over 64 cols) ----
    float p8[8];
    float tmax = -__builtin_inff();
#pragma unroll
    for (int c = 0; c < 8; ++c) {
      p8[c] = sS[smrow][smc0 + c];
      tmax = fmaxf(tmax, p8[c]);
    }
    tmax = fmaxf(tmax, __shfl_xor(tmax, 1));
    tmax = fmaxf(tmax, __shfl_xor(tmax, 2));
    tmax = fmaxf(tmax, __shfl_xor(tmax, 4));
    float m_new = fmaxf(m_run, tmax);
    float scale = __expf(m_run - m_new);
    float psum = 0.f;
    union { short s[8]; bf16x8 v; } pu;
#pragma unroll
    for (int c = 0; c < 8; ++c) {
      float p = __expf(p8[c] - m_new);
      psum += p;
      pu.s[c] = f2bf(p);
    }
    *(bf16x8*)(&sP[smrow][smc0]) = pu.v;
    psum += __shfl_xor(psum, 1);
    psum += __shfl_xor(psum, 2);
    psum += __shfl_xor(psum, 4);
    l_run = l_run * scale + psum;
    m_run = m_new;
    if ((tid & 7) == 0) sScale[smrow] = scale;
    BAR_LGKM();  // sP/sScale visible; stage + vstage still in flight
    // ---- PV: rescale accpv, then P @ feat (A=sP from LDS, B=vstage regs) ----
    float sc8[2][4];
#pragma unroll
    for (int rg = 0; rg < 2; ++rg)
#pragma unroll
      for (int r = 0; r < 4; ++r) sc8[rg][r] = sScale[rg * 16 + crow + r];
#pragma unroll
    for (int rg = 0; rg < 2; ++rg)
#pragma unroll
      for (int cf = 0; cf < 4; ++cf)
#pragma unroll
        for (int r = 0; r < 4; ++r) accpv[rg][cf][r] *= sc8[rg][r];
    bf16x8 pa[2][2];
#pragma unroll
    for (int rg = 0; rg < 2; ++rg)
#pragma unroll
      for (int kk = 0; kk < 2; ++kk)
        pa[rg][kk] = *(const bf16x8*)(&sP[rg * 16 + l15][kk * 32 + koff]);
#pragma unroll
    for (int kk = 0; kk < 2; ++kk)
#pragma unroll
      for (int rg = 0; rg < 2; ++rg)
#pragma unroll
        for (int cf = 0; cf < 4; ++cf)
          accpv[rg][cf] = __builtin_amdgcn_mfma_f32_16x16x32_bf16(
              pa[rg][kk], vstage[cf][kk], accpv[rg][cf], 0, 0, 0);
    __syncthreads();  // full drain: stage(t+1) complete, sS/sP reusable
  }
  // ---- emit partials ----
  if ((tid & 7) == 0) {
    mPart[chunk * NN + row0 + smrow] = m_run;
    lPart[chunk * NN + row0 + smrow] = l_run;
  }
  short* np = numPart + (size_t)chunk * NN * DD;
#pragma unroll
  for (int rg = 0; rg < 2; ++rg)
#pragma unroll
    for (int cf = 0; cf < 4; ++cf) {
      int col = w * 64 + cf * 16 + l15;
#pragma unroll
      for (int r = 0; r < 4; ++r)
        np[(size_t)(row0 + rg * 16 + crow + r) * DD + col] = f2bf(accpv[rg][cf][r]);
    }
}

// hp = (sum_i num_i * exp(m_i - m*)) / (sum_i l_i * exp(m_i - m*))
__global__ __launch_bounds__(256) void combine_kernel(
    const short* __restrict__ numPart, const float* __restrict__ mPart,
    const float* __restrict__ lPart, short* __restrict__ hp) {
  const int row = blockIdx.x;
  const int col = threadIdx.x;
  float m[NSPLIT], l[NSPLIT];
  float ms = -__builtin_inff();
#pragma unroll
  for (int i = 0; i < NSPLIT; ++i) {
    m[i] = mPart[i * NN + row];
    l[i] = lPart[i * NN + row];
    ms = fmaxf(ms, m[i]);
  }
  float denom = 0.f, num = 0.f;
  const size_t idx = (size_t)row * DD + col;
#pragma unroll
  for (int i = 0; i < NSPLIT; ++i) {
    float wgt = __expf(m[i] - ms);
    denom += l[i] * wgt;
    num += bf2f(numPart[(size_t)i * NN * DD + idx]) * wgt;
  }
  hp[idx] = f2bf(num / denom);
}

extern "C" void kernel_launch(void* const* d_in, const int* in_sizes, int n_in,
                              void* d_out, int out_size, void* d_ws, size_t ws_size,
                              hipStream_t stream) {
  const float* feat = (const float*)d_in[0];
  const int*   adj  = (const int*)d_in[1];
  const float* W    = (const float*)d_in[2];
  const float* a1   = (const float*)d_in[3];
  const float* a2   = (const float*)d_in[4];
  const float* a12  = (const float*)d_in[5];
  const float* W1   = (const float*)d_in[6];
  const float* W2   = (const float*)d_in[7];
  float* out = (float*)d_out;
  (void)in_sizes; (void)n_in; (void)out_size; (void)ws_size;

  char* ws = (char*)d_ws;
  size_t off = 0;
  auto alloc = [&](size_t b) { void* p = ws + off; off += (b + 255) & ~(size_t)255; return p; };
  short* featHi = (short*)alloc((size_t)NN * DD * 2);
  short* featLo = (short*)alloc((size_t)NN * DD * 2);
  short* fT     = (short*)alloc((size_t)NN * DD * 2);
  short* hHi    = (short*)alloc((size_t)NN * DD * 2);
  short* hLo    = (short*)alloc((size_t)NN * DD * 2);
  short* gHi    = (short*)alloc((size_t)NN * DD * 2);
  short* gLo    = (short*)alloc((size_t)NN * DD * 2);
  short* hp     = (short*)alloc((size_t)NN * DD * 2);
  short* WTh    = (short*)alloc((size_t)DD * DD * 2);
  short* WTl    = (short*)alloc((size_t)DD * DD * 2);
  short* A12Th  = (short*)alloc((size_t)DD * DD * 2);
  short* A12Tl  = (short*)alloc((size_t)DD * DD * 2);
  short* W1T    = (short*)alloc((size_t)DD * DD * 2);
  short* W2T    = (short*)alloc((size_t)DD * DD * 2);
  float* axv    = (float*)alloc((size_t)NN * 4);
  float* ayv    = (float*)alloc((size_t)NN * 4);
  short* numPart = (short*)alloc((size_t)NSPLIT * NN * DD * 2);
  float* mPart   = (float*)alloc((size_t)NSPLIT * NN * 4);
  float* lPart   = (float*)alloc((size_t)NSPLIT * NN * 4);

  cvt_split_kernel<<<2048, 256, 0, stream>>>(feat, featHi, featLo, NN * DD);
  featT_kernel<<<dim3(NN / 256, DD), 256, 0, stream>>>(feat, fT);
  transpose_split_kernel<<<DD, DD, 0, stream>>>(W, WTh, WTl);
  transpose_split_kernel<<<DD, DD, 0, stream>>>(a12, A12Th, A12Tl);
  transpose_split_kernel<<<DD, DD, 0, stream>>>(W1, W1T, nullptr);
  transpose_split_kernel<<<DD, DD, 0, stream>>>(W2, W2T, nullptr);
  gemm_bt64_kernel<<<dim3(NN / 64, DD / 64), 256, 0, stream>>>(
      featHi, featLo, WTh, WTl, nullptr, nullptr, hHi, hLo, nullptr, 0);
  gemm_bt64_kernel<<<dim3(NN / 64, DD / 64), 256, 0, stream>>>(
      hHi, hLo, A12Th, A12Tl, nullptr, nullptr, gHi, gLo, nullptr, 0);
  axay_kernel<<<NN / 4, 256, 0, stream>>>(hHi, hLo, a1, a2, axv, ayv);
  attn_kernel<<<dim3(NN / BM, NSPLIT), 256, 0, stream>>>(
      gHi, gLo, hHi, hLo, fT, axv, ayv, adj, numPart, mPart, lPart);
  combine_kernel<<<NN, DD, 0, stream>>>(numPart, mPart, lPart, hp);
  gemm_bt64_kernel<<<dim3(NN / 64, DD / 64), 256, 0, stream>>>(
      featHi, nullptr, W1T, nullptr, hp, W2T, nullptr, nullptr, out, 1);
}